// Round 2
// baseline (149.754 us; speedup 1.0000x reference)
//
#include <hip/hip_runtime.h>

#define BATCH 8
#define CH 512
#define C16 32
#define W 64
#define HWSZ 4096   // 64*64
#define NCH 4096    // BATCH*CH
#define LDS_STRIDE 68  // 64+4: rows stay 16B-aligned (272B), float4 reads 2-way max

#define NEG_INF (-__builtin_inff())

// ---------------- Kernel A: per-channel mean + atomic SE-hidden partials ----
// hacc[b*32+e] += mean(x[b,c]) * w1[e,c]   (fp reorder noise ok: blend is
// continuous across routing boundaries, so tiny s-perturbation -> tiny output)
__global__ __launch_bounds__(256) void gap_kernel(const float* __restrict__ x,
                                                  const float* __restrict__ w1,
                                                  float* __restrict__ hacc) {
    const int chan = blockIdx.x;
    const float* xp = x + (size_t)chan * HWSZ;
    const int t = threadIdx.x;
    float sum = 0.f;
#pragma unroll
    for (int j = 0; j < 4; ++j) {
        const float4 f = *(const float4*)(xp + t * 4 + j * 1024);
        sum += f.x + f.y + f.z + f.w;
    }
#pragma unroll
    for (int off = 32; off > 0; off >>= 1) sum += __shfl_down(sum, off, 64);
    __shared__ float ws[4];
    __shared__ float gm;
    if ((t & 63) == 0) ws[t >> 6] = sum;
    __syncthreads();
    if (t == 0) gm = (ws[0] + ws[1] + ws[2] + ws[3]) * (1.0f / HWSZ);
    __syncthreads();
    if (t < C16) {
        const int b = chan >> 9, c = chan & 511;
        atomicAdd(&hacc[b * C16 + t], gm * w1[t * CH + c]);
    }
}

// ---------------- Kernel B: routed dual maxpool + blend + residual ----------
__device__ __forceinline__ float4 max4(float4 a, float4 b) {
    return make_float4(fmaxf(a.x, b.x), fmaxf(a.y, b.y), fmaxf(a.z, b.z), fmaxf(a.w, b.w));
}

constexpr int lvl(int h) { return h <= 0 ? 0 : (h <= 1 ? 1 : (h <= 3 ? 2 : 3)); }

// Horizontal window-max half=Q for 16 px from v[32] (v covers pos-8..pos+23,
// -inf in out-of-row halo). Single pyramid, levels only up to lvl(Q).
template <int Q>
__device__ __forceinline__ void hpool_os(const float v[32], float os[16]) {
    constexpr int LS = lvl(Q);
    float m2[31], m4[29], m8[25];
    if constexpr (LS >= 1) {
#pragma unroll
        for (int j = 3; j <= 27; ++j) m2[j] = fmaxf(v[j], v[j + 1]);
    }
    if constexpr (LS >= 2) {
#pragma unroll
        for (int j = 3; j <= 25; ++j) m4[j] = fmaxf(m2[j], m2[j + 2]);
    }
    if constexpr (LS >= 3) {
#pragma unroll
        for (int j = 3; j <= 21; ++j) m8[j] = fmaxf(m4[j], m4[j + 4]);
    }
#pragma unroll
    for (int i = 0; i < 16; ++i) {
        const int pos = 8 + i;
        constexpr int P = 1 << LS;
        const int a = pos - Q, b = pos + Q - P + 1;
        if constexpr (LS == 0) os[i] = v[pos];
        else if constexpr (LS == 1) os[i] = fmaxf(m2[a], m2[b]);
        else if constexpr (LS == 2) os[i] = fmaxf(m4[a], m4[b]);
        else os[i] = fmaxf(m8[a], m8[b]);
    }
}

// Vertical window-max half=H over LDS rows (clamp == SAME pad for max),
// streaming pre/core/post: peak ~7 live float4 instead of a 31-float4 pyramid.
template <int H>
__device__ __forceinline__ void vpass(const float* __restrict__ buf, int x0, int y0,
                                      float4 o[4]) {
    auto rd = [&](int row) {
        row = row < 0 ? 0 : (row > 63 ? 63 : row);
        return *(const float4*)(buf + row * LDS_STRIDE + x0);
    };
    if constexpr (H == 0) {
#pragma unroll
        for (int i = 0; i < 4; ++i) o[i] = rd(y0 + i);
    } else if constexpr (H == 1) {
        const float4 r0 = rd(y0 - 1), r1 = rd(y0), r2 = rd(y0 + 1);
        const float4 r3 = rd(y0 + 2), r4 = rd(y0 + 3), r5 = rd(y0 + 4);
        const float4 a0 = max4(r0, r1), a1 = max4(r1, r2), a2 = max4(r2, r3);
        const float4 a3 = max4(r3, r4), a4 = max4(r4, r5);
        o[0] = max4(a0, a1); o[1] = max4(a1, a2); o[2] = max4(a2, a3); o[3] = max4(a3, a4);
    } else {
        // suffix maxes of the 3 rows below the common core
        const float4 pre2 = rd(y0 + 2 - H);
        const float4 pre1 = max4(rd(y0 + 1 - H), pre2);
        const float4 pre0 = max4(rd(y0 - H), pre1);
        // core rows [y0+3-H, y0+H] : 2H-2 rows, common to all 4 outputs
        float4 core = rd(y0 + 3 - H);
#pragma unroll
        for (int d = 1; d <= 2 * H - 3; ++d) core = max4(core, rd(y0 + 3 - H + d));
        o[0] = max4(pre0, core);
        float4 post = rd(y0 + H + 1);
        o[1] = max4(max4(pre1, core), post);
        post = max4(post, rd(y0 + H + 2));
        o[2] = max4(max4(pre2, core), post);
        post = max4(post, rd(y0 + H + 3));
        o[3] = max4(core, post);
    }
}

template <int Q>
__device__ __forceinline__ void pool_body(const float v[32], float* hs, float* hb,
                                          const float* __restrict__ xp,
                                          float* __restrict__ op, float fb, float fs) {
    const int t = threadIdx.x;
    const int r = t >> 2, seg = t & 3;
    float os[16];
    hpool_os<Q>(v, os);
    float* hsp = hs + r * LDS_STRIDE + seg * 16;
    float* hbp = hb + r * LDS_STRIDE + seg * 16;
#pragma unroll
    for (int j = 0; j < 4; ++j) {
        *(float4*)(hsp + 4 * j) = make_float4(os[4*j], os[4*j+1], os[4*j+2], os[4*j+3]);
        float4 bo;  // window half Q+1 = max(window half Q, two edge elems)
        bo.x = fmaxf(os[4*j+0], fmaxf(v[8+4*j+0 - Q - 1], v[8+4*j+0 + Q + 1]));
        bo.y = fmaxf(os[4*j+1], fmaxf(v[8+4*j+1 - Q - 1], v[8+4*j+1 + Q + 1]));
        bo.z = fmaxf(os[4*j+2], fmaxf(v[8+4*j+2 - Q - 1], v[8+4*j+2 + Q + 1]));
        bo.w = fmaxf(os[4*j+3], fmaxf(v[8+4*j+3 - Q - 1], v[8+4*j+3 + Q + 1]));
        *(float4*)(hbp + 4 * j) = bo;
    }
    __syncthreads();
    const int cg = t & 15, rb = t >> 4;
    const int x0 = cg * 4, y0 = rb * 4;
    float4 vs4[4], vb4[4];
    vpass<Q>(hs, x0, y0, vs4);
    vpass<Q + 1>(hb, x0, y0, vb4);
#pragma unroll
    for (int i = 0; i < 4; ++i) {
        const float4 xv = *(const float4*)(xp + (y0 + i) * W + x0);
        float4 o;
        o.x = fb * vb4[i].x + fs * vs4[i].x + xv.x;
        o.y = fb * vb4[i].y + fs * vs4[i].y + xv.y;
        o.z = fb * vb4[i].z + fs * vs4[i].z + xv.z;
        o.w = fb * vb4[i].w + fs * vs4[i].w + xv.w;
        *(float4*)(op + (y0 + i) * W + x0) = o;
    }
}

__global__ __launch_bounds__(256, 4) void pool_kernel(const float* __restrict__ x,
                                                      const float* __restrict__ hacc,
                                                      const float* __restrict__ b1,
                                                      const float* __restrict__ w2,
                                                      const float* __restrict__ b2,
                                                      float* __restrict__ out) {
    __shared__ float hs[64 * LDS_STRIDE];
    __shared__ float hb[64 * LDS_STRIDE];
    __shared__ float ssc;
    const int chan = blockIdx.x;  // block-uniform routing -> zero divergence
    const int t = threadIdx.x;
    const int b = chan >> 9, c = chan & 511;

    // ---- score prologue: s = relu(b2[c] + relu(hacc+b1) . w2[c,:]) ----
    if (t < C16) {
        const float h = fmaxf(hacc[b * C16 + t] + b1[t], 0.f);
        float p = h * w2[c * C16 + t];
#pragma unroll
        for (int off = 16; off > 0; off >>= 1) p += __shfl_down(p, off, 64);
        if (t == 0) ssc = fmaxf(p + b2[c], 0.f);
    }
    __syncthreads();
    const float s = ssc;
    int q = (int)floorf(s);
    q = q < 0 ? 0 : (q > 5 ? 5 : q);
    const float fb = s - (float)q;        // weight on larger kernel (may exceed 1)
    const float fs = (float)(q + 1) - s;  // weight on smaller kernel (may be <0)

    const float* xp = x + (size_t)chan * HWSZ;
    float* op = out + (size_t)chan * HWSZ;

    const int r = t >> 2, seg = t & 3;
    float v[32];
    const float* rowp = xp + r * W;
#pragma unroll
    for (int j = 0; j < 8; ++j) {
        const int p = seg * 16 - 8 + j * 4;
        if (p >= 0 && p < W) {
            const float4 f = *(const float4*)(rowp + p);
            v[4*j] = f.x; v[4*j+1] = f.y; v[4*j+2] = f.z; v[4*j+3] = f.w;
        } else {
            v[4*j] = NEG_INF; v[4*j+1] = NEG_INF; v[4*j+2] = NEG_INF; v[4*j+3] = NEG_INF;
        }
    }
    switch (q) {
        case 0: pool_body<0>(v, hs, hb, xp, op, fb, fs); break;
        case 1: pool_body<1>(v, hs, hb, xp, op, fb, fs); break;
        case 2: pool_body<2>(v, hs, hb, xp, op, fb, fs); break;
        case 3: pool_body<3>(v, hs, hb, xp, op, fb, fs); break;
        case 4: pool_body<4>(v, hs, hb, xp, op, fb, fs); break;
        default: pool_body<5>(v, hs, hb, xp, op, fb, fs); break;
    }
}

extern "C" void kernel_launch(void* const* d_in, const int* in_sizes, int n_in,
                              void* d_out, int out_size, void* d_ws, size_t ws_size,
                              hipStream_t stream) {
    const float* x  = (const float*)d_in[0];
    const float* w1 = (const float*)d_in[1];
    const float* b1 = (const float*)d_in[2];
    const float* w2 = (const float*)d_in[3];
    const float* b2 = (const float*)d_in[4];
    float* out = (float*)d_out;
    float* hacc = (float*)d_ws;  // 8*32 floats, must be zeroed (ws is 0xAA-poisoned)

    hipMemsetAsync(hacc, 0, BATCH * C16 * sizeof(float), stream);
    gap_kernel<<<NCH, 256, 0, stream>>>(x, w1, hacc);
    pool_kernel<<<NCH, 256, 0, stream>>>(x, hacc, b1, w2, b2, out);
}

// Round 4
// 146.609 us; speedup vs baseline: 1.0215x; 1.0215x over previous
//
#include <hip/hip_runtime.h>

#define BATCH 8
#define CH 512
#define C16 32
#define W 64
#define HWSZ 4096   // 64*64
#define NCH 4096    // BATCH*CH
#define LDS_STRIDE 68  // 64+4: rows stay 16B-aligned (272B), float4 reads 2-way max

#define NEG_INF (-__builtin_inff())

typedef float nfloat4 __attribute__((ext_vector_type(4)));  // for nontemporal built-in

// ---------------- Kernel A: per-channel mean + atomic SE-hidden partials ----
// hacc[b*32+e] += mean(x[b,c]) * w1[e,c]   (fp reorder noise ok: blend is
// continuous across routing boundaries, so tiny s-perturbation -> tiny output)
__global__ __launch_bounds__(256) void gap_kernel(const float* __restrict__ x,
                                                  const float* __restrict__ w1,
                                                  float* __restrict__ hacc) {
    const int chan = blockIdx.x;
    const float* xp = x + (size_t)chan * HWSZ;
    const int t = threadIdx.x;
    float sum = 0.f;
#pragma unroll
    for (int j = 0; j < 4; ++j) {
        const float4 f = *(const float4*)(xp + t * 4 + j * 1024);
        sum += f.x + f.y + f.z + f.w;
    }
#pragma unroll
    for (int off = 32; off > 0; off >>= 1) sum += __shfl_down(sum, off, 64);
    __shared__ float ws[4];
    __shared__ float gm;
    if ((t & 63) == 0) ws[t >> 6] = sum;
    __syncthreads();
    if (t == 0) gm = (ws[0] + ws[1] + ws[2] + ws[3]) * (1.0f / HWSZ);
    __syncthreads();
    if (t < C16) {
        const int b = chan >> 9, c = chan & 511;
        atomicAdd(&hacc[b * C16 + t], gm * w1[t * CH + c]);
    }
}

// ---------------- Kernel B: routed dual maxpool + blend + residual ----------
__device__ __forceinline__ float4 max4(float4 a, float4 b) {
    return make_float4(fmaxf(a.x, b.x), fmaxf(a.y, b.y), fmaxf(a.z, b.z), fmaxf(a.w, b.w));
}

constexpr int lvl(int h) { return h <= 0 ? 0 : (h <= 1 ? 1 : (h <= 3 ? 2 : 3)); }

// Horizontal window-max half=Q for 16 px from v[32] (v covers pos-8..pos+23,
// -inf in out-of-row halo). Single pyramid, levels only up to lvl(Q).
template <int Q>
__device__ __forceinline__ void hpool_os(const float v[32], float os[16]) {
    constexpr int LS = lvl(Q);
    float m2[31], m4[29], m8[25];
    if constexpr (LS >= 1) {
#pragma unroll
        for (int j = 3; j <= 27; ++j) m2[j] = fmaxf(v[j], v[j + 1]);
    }
    if constexpr (LS >= 2) {
#pragma unroll
        for (int j = 3; j <= 25; ++j) m4[j] = fmaxf(m2[j], m2[j + 2]);
    }
    if constexpr (LS >= 3) {
#pragma unroll
        for (int j = 3; j <= 21; ++j) m8[j] = fmaxf(m4[j], m4[j + 4]);
    }
#pragma unroll
    for (int i = 0; i < 16; ++i) {
        const int pos = 8 + i;
        constexpr int P = 1 << LS;
        const int a = pos - Q, b = pos + Q - P + 1;
        if constexpr (LS == 0) os[i] = v[pos];
        else if constexpr (LS == 1) os[i] = fmaxf(m2[a], m2[b]);
        else if constexpr (LS == 2) os[i] = fmaxf(m4[a], m4[b]);
        else os[i] = fmaxf(m8[a], m8[b]);
    }
}

// Vertical window-max half=H over LDS rows (clamp == SAME pad for max),
// streaming pre/core/post: peak ~7 live float4 instead of a 31-float4 pyramid.
template <int H>
__device__ __forceinline__ void vpass(const float* __restrict__ buf, int x0, int y0,
                                      float4 o[4]) {
    auto rd = [&](int row) {
        row = row < 0 ? 0 : (row > 63 ? 63 : row);
        return *(const float4*)(buf + row * LDS_STRIDE + x0);
    };
    if constexpr (H == 0) {
#pragma unroll
        for (int i = 0; i < 4; ++i) o[i] = rd(y0 + i);
    } else if constexpr (H == 1) {
        const float4 r0 = rd(y0 - 1), r1 = rd(y0), r2 = rd(y0 + 1);
        const float4 r3 = rd(y0 + 2), r4 = rd(y0 + 3), r5 = rd(y0 + 4);
        const float4 a0 = max4(r0, r1), a1 = max4(r1, r2), a2 = max4(r2, r3);
        const float4 a3 = max4(r3, r4), a4 = max4(r4, r5);
        o[0] = max4(a0, a1); o[1] = max4(a1, a2); o[2] = max4(a2, a3); o[3] = max4(a3, a4);
    } else {
        // suffix maxes of the 3 rows below the common core
        const float4 pre2 = rd(y0 + 2 - H);
        const float4 pre1 = max4(rd(y0 + 1 - H), pre2);
        const float4 pre0 = max4(rd(y0 - H), pre1);
        // core rows [y0+3-H, y0+H] : 2H-2 rows, common to all 4 outputs
        float4 core = rd(y0 + 3 - H);
#pragma unroll
        for (int d = 1; d <= 2 * H - 3; ++d) core = max4(core, rd(y0 + 3 - H + d));
        o[0] = max4(pre0, core);
        float4 post = rd(y0 + H + 1);
        o[1] = max4(max4(pre1, core), post);
        post = max4(post, rd(y0 + H + 2));
        o[2] = max4(max4(pre2, core), post);
        post = max4(post, rd(y0 + H + 3));
        o[3] = max4(core, post);
    }
}

template <int Q>
__device__ __forceinline__ void pool_body(const float v[32], float* hs, float* hb,
                                          const float* __restrict__ xp,
                                          float* __restrict__ op, float fb, float fs) {
    const int t = threadIdx.x;
    const int r = t >> 2, seg = t & 3;
    float os[16];
    hpool_os<Q>(v, os);
    float* hsp = hs + r * LDS_STRIDE + seg * 16;
    float* hbp = hb + r * LDS_STRIDE + seg * 16;
#pragma unroll
    for (int j = 0; j < 4; ++j) {
        *(float4*)(hsp + 4 * j) = make_float4(os[4*j], os[4*j+1], os[4*j+2], os[4*j+3]);
        float4 bo;  // window half Q+1 = max(window half Q, two edge elems)
        bo.x = fmaxf(os[4*j+0], fmaxf(v[8+4*j+0 - Q - 1], v[8+4*j+0 + Q + 1]));
        bo.y = fmaxf(os[4*j+1], fmaxf(v[8+4*j+1 - Q - 1], v[8+4*j+1 + Q + 1]));
        bo.z = fmaxf(os[4*j+2], fmaxf(v[8+4*j+2 - Q - 1], v[8+4*j+2 + Q + 1]));
        bo.w = fmaxf(os[4*j+3], fmaxf(v[8+4*j+3 - Q - 1], v[8+4*j+3 + Q + 1]));
        *(float4*)(hbp + 4 * j) = bo;
    }
    __syncthreads();
    const int cg = t & 15, rb = t >> 4;
    const int x0 = cg * 4, y0 = rb * 4;
    float4 vs4[4], vb4[4];
    vpass<Q>(hs, x0, y0, vs4);
    vpass<Q + 1>(hb, x0, y0, vb4);
#pragma unroll
    for (int i = 0; i < 4; ++i) {
        const float4 xv = *(const float4*)(xp + (y0 + i) * W + x0);  // L1/L2 hit
        nfloat4 o;
        o.x = fb * vb4[i].x + fs * vs4[i].x + xv.x;
        o.y = fb * vb4[i].y + fs * vs4[i].y + xv.y;
        o.z = fb * vb4[i].z + fs * vs4[i].z + xv.z;
        o.w = fb * vb4[i].w + fs * vs4[i].w + xv.w;
        // write-once data: nontemporal, don't pollute L2
        __builtin_nontemporal_store(o, (nfloat4*)(op + (y0 + i) * W + x0));
    }
}

// launch_bounds(256,2): 256-VGPR cap (no spills on Q=4/5 paths), >=2 blocks/CU.
// (256,4) in R2 capped at 128 VGPR -> scratch spills -> +10us regression.
__global__ __launch_bounds__(256, 2) void pool_kernel(const float* __restrict__ x,
                                                      const float* __restrict__ hacc,
                                                      const float* __restrict__ b1,
                                                      const float* __restrict__ w2,
                                                      const float* __restrict__ b2,
                                                      float* __restrict__ out) {
    __shared__ float hs[64 * LDS_STRIDE];
    __shared__ float hb[64 * LDS_STRIDE];
    __shared__ float ssc;
    const int chan = blockIdx.x;  // block-uniform routing -> zero divergence
    const int t = threadIdx.x;
    const int b = chan >> 9, c = chan & 511;

    const float* xp = x + (size_t)chan * HWSZ;
    float* op = out + (size_t)chan * HWSZ;

    // ---- issue x loads FIRST so they're in flight during the score calc ----
    const int r = t >> 2, seg = t & 3;
    float v[32];
    const float* rowp = xp + r * W;
#pragma unroll
    for (int j = 0; j < 8; ++j) {
        const int p = seg * 16 - 8 + j * 4;
        if (p >= 0 && p < W) {
            const float4 f = *(const float4*)(rowp + p);
            v[4*j] = f.x; v[4*j+1] = f.y; v[4*j+2] = f.z; v[4*j+3] = f.w;
        } else {
            v[4*j] = NEG_INF; v[4*j+1] = NEG_INF; v[4*j+2] = NEG_INF; v[4*j+3] = NEG_INF;
        }
    }

    // ---- score: s = relu(b2[c] + relu(hacc+b1) . w2[c,:]) ----
    if (t < C16) {
        const float h = fmaxf(hacc[b * C16 + t] + b1[t], 0.f);
        float p = h * w2[c * C16 + t];
#pragma unroll
        for (int off = 16; off > 0; off >>= 1) p += __shfl_down(p, off, 64);
        if (t == 0) ssc = fmaxf(p + b2[c], 0.f);
    }
    __syncthreads();
    const float s = ssc;
    int q = (int)floorf(s);
    q = q < 0 ? 0 : (q > 5 ? 5 : q);
    const float fb = s - (float)q;        // weight on larger kernel
    const float fs = (float)(q + 1) - s;  // weight on smaller kernel

    switch (q) {
        case 0: pool_body<0>(v, hs, hb, xp, op, fb, fs); break;
        case 1: pool_body<1>(v, hs, hb, xp, op, fb, fs); break;
        case 2: pool_body<2>(v, hs, hb, xp, op, fb, fs); break;
        case 3: pool_body<3>(v, hs, hb, xp, op, fb, fs); break;
        case 4: pool_body<4>(v, hs, hb, xp, op, fb, fs); break;
        default: pool_body<5>(v, hs, hb, xp, op, fb, fs); break;
    }
}

extern "C" void kernel_launch(void* const* d_in, const int* in_sizes, int n_in,
                              void* d_out, int out_size, void* d_ws, size_t ws_size,
                              hipStream_t stream) {
    const float* x  = (const float*)d_in[0];
    const float* w1 = (const float*)d_in[1];
    const float* b1 = (const float*)d_in[2];
    const float* w2 = (const float*)d_in[3];
    const float* b2 = (const float*)d_in[4];
    float* out = (float*)d_out;
    float* hacc = (float*)d_ws;  // 8*32 floats, must be zeroed (ws is 0xAA-poisoned)

    (void)hipMemsetAsync(hacc, 0, BATCH * C16 * sizeof(float), stream);
    gap_kernel<<<NCH, 256, 0, stream>>>(x, w1, hacc);
    pool_kernel<<<NCH, 256, 0, stream>>>(x, hacc, b1, w2, b2, out);
}